// Round 15
// baseline (436.868 us; speedup 1.0000x reference)
//
#include <hip/hip_runtime.h>

#define E_ 2
#define HQ_ 16
#define HK_ 8
#define HD_ 128
#define DIM_ 2048
#define BS_ 2
#define SEQ_ 2048
#define NTOK 4096

typedef unsigned short ushort_t;
typedef short bf16x8 __attribute__((ext_vector_type(8)));
typedef unsigned short ushort8 __attribute__((ext_vector_type(8)));
typedef float f32x4 __attribute__((ext_vector_type(4)));

#define MFMA(a, b, c) __builtin_amdgcn_mfma_f32_16x16x32_bf16(a, b, c, 0, 0, 0)

__device__ __forceinline__ unsigned short f2bf(float f) {
  unsigned u = __builtin_bit_cast(unsigned, f);
  u = (u + 0x7FFFu + ((u >> 16) & 1u)) >> 16;
  return (unsigned short)u;
}
__device__ __forceinline__ float bf2f(unsigned short h) {
  unsigned u = ((unsigned)h) << 16;
  return __builtin_bit_cast(float, u);
}

__device__ __forceinline__ void glds16(const void* g, void* s) {
  __builtin_amdgcn_global_load_lds(
      (const __attribute__((address_space(1))) unsigned int*)g,
      (__attribute__((address_space(3))) unsigned int*)s, 16, 0, 0);
}

// ---------------- token -> compact row (expert-0 rows first), deterministic scan ----------------
__global__ __launch_bounds__(1024) void build_crow(const int* __restrict__ ids,
                                                   int* __restrict__ cnt, int* __restrict__ crow) {
  __shared__ int sc[1024];
  __shared__ int total0;
  const int t = threadIdx.x;
  int id4[4];
  int c = 0;
  for (int j = 0; j < 4; j++) {
    id4[j] = ids[t * 4 + j];
    c += (id4[j] == 0);
  }
  sc[t] = c;
  __syncthreads();
  for (int off = 1; off < 1024; off <<= 1) {
    int v = sc[t];
    int add = (t >= off) ? sc[t - off] : 0;
    __syncthreads();
    sc[t] = v + add;
    __syncthreads();
  }
  if (t == 1023) total0 = sc[1023];
  __syncthreads();
  const int cnt0 = total0;
  if (t == 0) {
    cnt[0] = cnt0;
    cnt[1] = NTOK - cnt0;
  }
  int p0 = sc[t] - c;
  int r0 = 0;
  for (int j = 0; j < 4; j++) {
    int n = t * 4 + j;
    int cr;
    if (id4[j] == 0) {
      cr = p0 + r0;
      r0++;
    } else {
      cr = cnt0 + (n - (p0 + r0));
    }
    crow[n] = cr;
  }
}

// ---------------- x fp32 -> bf16, scattered into compact row order ----------------
__global__ __launch_bounds__(256) void convert_scatter(const float* __restrict__ x,
                                                       const int* __restrict__ crow,
                                                       ushort_t* __restrict__ xb) {
  const int token = blockIdx.x;
  const int cr = crow[token];
  const long src = (long)token * DIM_ + threadIdx.x * 8;
  const long dst = (long)cr * DIM_ + threadIdx.x * 8;
  float4 a = *(const float4*)(x + src);
  float4 b = *(const float4*)(x + src + 4);
  ushort8 o;
  o[0] = f2bf(a.x); o[1] = f2bf(a.y); o[2] = f2bf(a.z); o[3] = f2bf(a.w);
  o[4] = f2bf(b.x); o[5] = f2bf(b.y); o[6] = f2bf(b.z); o[7] = f2bf(b.w);
  *(ushort8*)(xb + dst) = o;
}

// ---------------- merged wq/wk/wv [e][K][N] fp32 -> wqkvT [e][outBase+n][K] bf16 ----------------
__global__ __launch_bounds__(256) void transpose_w3(const float* __restrict__ wq,
                                                    const float* __restrict__ wk,
                                                    const float* __restrict__ wv,
                                                    ushort_t* __restrict__ out) {
  __shared__ float tile[32][33];
  const int e = blockIdx.z;
  const int xx = blockIdx.x;
  const float* inp;
  int N, outBase, n0;
  if (xx < 64) {
    inp = wq + (long)e * 2048 * 2048; N = 2048; outBase = 0;    n0 = xx * 32;
  } else if (xx < 96) {
    inp = wk + (long)e * 2048 * 1024; N = 1024; outBase = 2048; n0 = (xx - 64) * 32;
  } else {
    inp = wv + (long)e * 2048 * 1024; N = 1024; outBase = 3072; n0 = (xx - 96) * 32;
  }
  ushort_t* outp = out + (long)e * 4096 * 2048;
  const int k0 = blockIdx.y * 32;
  const int tx = threadIdx.x & 31, ty = threadIdx.x >> 5;
  for (int i = 0; i < 4; i++)
    tile[ty + i * 8][tx] = inp[(long)(k0 + ty + i * 8) * N + n0 + tx];
  __syncthreads();
  for (int i = 0; i < 4; i++)
    outp[(long)(outBase + n0 + ty + i * 8) * 2048 + k0 + tx] = f2bf(tile[tx][ty + i * 8]);
}

// ---------------- W [e][K][N] fp32 -> W^T [e][outBase+n][K] bf16 (wo only) ----------------
__global__ __launch_bounds__(256) void transpose_f2b(const float* __restrict__ in,
                                                     ushort_t* __restrict__ out, int K, int N,
                                                     long inE, long outE, int outBase) {
  __shared__ float tile[32][33];
  int e = blockIdx.z;
  const float* inp = in + (long)e * inE;
  ushort_t* outp = out + (long)e * outE;
  int n0 = blockIdx.x * 32, k0 = blockIdx.y * 32;
  int tx = threadIdx.x & 31, ty = threadIdx.x >> 5;
  for (int i = 0; i < 4; i++)
    tile[ty + i * 8][tx] = inp[(long)(k0 + ty + i * 8) * N + n0 + tx];
  __syncthreads();
  for (int i = 0; i < 4; i++)
    outp[(long)(outBase + n0 + ty + i * 8) * K + k0 + tx] = f2bf(tile[tx][ty + i * 8]);
}

// ---------------- v slice of qkv_raw (compact rows) -> V^T [b][hk][d][s] bf16 ----------------
__global__ __launch_bounds__(256) void transpose_v(const ushort_t* __restrict__ qkv,
                                                   const int* __restrict__ crow,
                                                   ushort_t* __restrict__ vt) {
  __shared__ ushort_t tile[32][34];
  int z = blockIdx.z;
  int b = z / HK_, hk = z % HK_;
  int s0 = blockIdx.x * 32, d0 = blockIdx.y * 32;
  int tx = threadIdx.x & 31, ty = threadIdx.x >> 5;
  for (int i = 0; i < 4; i++) {
    int cr = crow[b * SEQ_ + s0 + ty + i * 8];
    tile[ty + i * 8][tx] = qkv[(long)cr * 4096 + 3072 + hk * 128 + d0 + tx];
  }
  __syncthreads();
  for (int i = 0; i < 4; i++)
    vt[((long)(b * HK_ + hk) * 128 + d0 + ty + i * 8) * SEQ_ + s0 + tx] = tile[tx][ty + i * 8];
}

// ---------------- per-expert GEMM, 128x128 tile, 4 waves, 64x64/wave, 3 blocks/CU ----------
// R12 engine verbatim (reproduced twice at 431.7/432.3 us total). The ~660 TF level is the
// 2-phase-class structural plateau for these K=2048 per-expert shapes; parked.
__global__ __launch_bounds__(256, 3) void gemm_bt_slot(const ushort_t* __restrict__ A,
                                                       const ushort_t* __restrict__ BT,
                                                       ushort_t* __restrict__ C, int K, int Nc,
                                                       const int* __restrict__ cnt, long btE) {
  __shared__ __align__(16) char lds[49152];
  const int cnt0 = cnt[0];
  const int nA = (cnt0 + 127) >> 7;
  const int slot = blockIdx.y, bn = blockIdx.x;
  const int e = (slot < nA) ? 0 : 1;
  const int bm = e ? slot - nA : slot;
  const int scnt = e ? (NTOK - cnt0) : cnt0;
  if (bm * 128 >= scnt) return;
  const int sbase = e ? cnt0 : 0;
  const ushort_t* Bte = BT + (long)e * btE;

  const int t = threadIdx.x, w = t >> 6, lane = t & 63;
  const int quad = lane >> 4, l16 = lane & 15;
  const int wr = w >> 1, wc = w & 1;  // wave grid: 2 (M of 64) x 2 (N of 64)

  const int arow0 = sbase + bm * 128;
  const int brow0 = bn * 128;

  // staging: unit = 128 rows x 32 k (64B rows, 4x16B chunks, rotate row>>1).
  const int srow = t >> 2;                       // 0..63
  const int lc = ((t & 3) - (srow >> 1)) & 3;    // chunk landing at this thread's slot
  int ga1 = arow0 + srow;       if (ga1 > NTOK - 1) ga1 = NTOK - 1;
  int ga2 = arow0 + 64 + srow;  if (ga2 > NTOK - 1) ga2 = NTOK - 1;
  const ushort_t* sA1 = A + (long)ga1 * K + lc * 8;
  const ushort_t* sA2 = A + (long)ga2 * K + lc * 8;
  const ushort_t* sB1 = Bte + (long)(brow0 + srow) * K + lc * 8;
  const ushort_t* sB2 = Bte + (long)(brow0 + 64 + srow) * K + lc * 8;

  f32x4 acc[4][4];
#pragma unroll
  for (int i = 0; i < 4; i++)
#pragma unroll
    for (int j = 0; j < 4; j++) acc[i][j] = (f32x4){0.f, 0.f, 0.f, 0.f};

#define STAGE(ps, kk)                                \
  glds16(sA1 + (kk), (ps) + w * 1024);               \
  glds16(sA2 + (kk), (ps) + 4096 + w * 1024);        \
  glds16(sB1 + (kk), (ps) + 8192 + w * 1024);        \
  glds16(sB2 + (kk), (ps) + 12288 + w * 1024);

  char* pr = lds;
  char* pn = lds + 16384;
  char* p2 = lds + 32768;

  // prologue: stage kt0, kt1; wait kt0 complete (4 of 8 outstanding)
  STAGE(pr, 0);
  STAGE(pn, 32);
  asm volatile("s_waitcnt vmcnt(4)" ::: "memory");
  __builtin_amdgcn_s_barrier();

  const int NT = K >> 5;
  for (int kt = 0; kt < NT; kt++) {
    const bool st = (kt + 2) < NT;
    if (st) { STAGE(p2, (kt + 2) * 32); }
    bf16x8 af[4], bfv[4];
#pragma unroll
    for (int mf = 0; mf < 4; mf++) {
      const int lr = wr * 64 + mf * 16 + l16;
      af[mf] = *(const bf16x8*)(pr + lr * 64 + ((quad + (lr >> 1)) & 3) * 16);
    }
#pragma unroll
    for (int nf = 0; nf < 4; nf++) {
      const int c = wc * 64 + nf * 16 + l16;
      bfv[nf] = *(const bf16x8*)(pr + 8192 + c * 64 + ((quad + (c >> 1)) & 3) * 16);
    }
    asm volatile("s_waitcnt lgkmcnt(0)" ::: "memory");
    __builtin_amdgcn_sched_barrier(0);
    __builtin_amdgcn_s_setprio(1);
#pragma unroll
    for (int mf = 0; mf < 4; mf++)
#pragma unroll
      for (int nf = 0; nf < 4; nf++) acc[mf][nf] = MFMA(af[mf], bfv[nf], acc[mf][nf]);
    __builtin_amdgcn_s_setprio(0);
    if (st) asm volatile("s_waitcnt vmcnt(4)" ::: "memory");
    else    asm volatile("s_waitcnt vmcnt(0)" ::: "memory");
    __builtin_amdgcn_s_barrier();
    char* tmp = pr; pr = pn; pn = p2; p2 = tmp;
  }
#undef STAGE

  // epilogue: C/D layout col=lane&15, row=quad*4+reg
#pragma unroll
  for (int mf = 0; mf < 4; mf++) {
#pragma unroll
    for (int reg = 0; reg < 4; reg++) {
      const int rl = wr * 64 + mf * 16 + quad * 4 + reg;
      if (bm * 128 + rl >= scnt) continue;
      ushort_t* Cp = C + (long)(arow0 + rl) * Nc + brow0 + wc * 64 + l16;
#pragma unroll
      for (int nf = 0; nf < 4; nf++) Cp[nf * 16] = f2bf(acc[mf][nf][reg]);
    }
  }
}

// ---------------- per-head RMSNorm + RoPE, one block per token ----------------
// Round 15: was grid (4096 x 6) = 24,576 blocks with ~1KB payload each -> dispatch-rate-bound,
// and fc/fs/e/cr re-loaded 24x per token. Now one block per token; each of the 4 waves loops
// over 6 head-slots (slot = w + 4*i covers 0..23 exactly). Per-slot body identical; token-level
// values (e, cr, cos/sin) hoisted out of the loop.
__global__ __launch_bounds__(256) void fuse_rmsrope(
    const ushort_t* __restrict__ qkv, const int* __restrict__ crow, const float* __restrict__ qw,
    const float* __restrict__ kw, const float* __restrict__ fc, const float* __restrict__ fs,
    const int* __restrict__ ids, ushort_t* __restrict__ qout, ushort_t* __restrict__ kout) {
  const int token = blockIdx.x;
  const int w = threadIdx.x >> 6;
  const int lane = threadIdx.x & 63;
  const int b = token >> 11, s = token & 2047;
  const int e = ids[token];
  const int cr = crow[token];
  const float c = fc[s * 64 + lane], sn = fs[s * 64 + lane];
  const ushort_t* rowbase = qkv + (long)cr * 4096;
  const float* qwe = qw + e * 128;
  const float* kwe = kw + e * 128;

#pragma unroll
  for (int i = 0; i < 6; i++) {
    const int slot = w + i * 4;  // 0..23
    const bool isq = slot < 16;
    const int h = isq ? slot : slot - 16;
    const ushort_t* src = rowbase + (isq ? slot * 128 : 2048 + h * 128);
    unsigned pv = *(const unsigned*)(src + 2 * lane);
    float v0 = bf2f((unsigned short)pv), v1 = bf2f((unsigned short)(pv >> 16));
    float ss = v0 * v0 + v1 * v1;
    ss += __shfl_xor(ss, 32); ss += __shfl_xor(ss, 16); ss += __shfl_xor(ss, 8);
    ss += __shfl_xor(ss, 4);  ss += __shfl_xor(ss, 2);  ss += __shfl_xor(ss, 1);
    float r = rsqrtf(ss * (1.0f / 128.0f) + 1e-6f);
    const float* nw = isq ? qwe : kwe;
    v0 *= r * nw[2 * lane];
    v1 *= r * nw[2 * lane + 1];
    float o0 = v0 * c - v1 * sn;
    float o1 = v0 * sn + v1 * c;
    ushort_t* dst;
    if (isq) {
      const float QS = 0.08838834764831845f * 1.4426950408889634f;  // 1/sqrt(128)*log2(e)
      o0 *= QS; o1 *= QS;
      dst = qout + ((long)(b * HQ_ + h) * SEQ_ + s) * 128;
    } else {
      dst = kout + ((long)(b * HK_ + h) * SEQ_ + s) * 128;
    }
    *(unsigned*)(dst + 2 * lane) = (unsigned)f2bf(o0) | ((unsigned)f2bf(o1) << 16);
  }
}

// ---------------- causal GQA flash attention, BM=BN=64 ----------------
// (validated: paired q-tiles, 2-phase double-buffered K/V staging, setprio on MFMA clusters)
__global__ __launch_bounds__(256, 2) void attn_kernel(const ushort_t* __restrict__ Q,
                                                      const ushort_t* __restrict__ K,
                                                      const ushort_t* __restrict__ VT,
                                                      const int* __restrict__ crow,
                                                      ushort_t* __restrict__ O) {
  __shared__ __align__(16) ushort_t Ks[2][64 * 128];
  __shared__ __align__(16) ushort_t Vs[2][128 * 64];
  __shared__ __align__(16) ushort_t Ps[4][16][72];  // per-wave P, padded stride

  const int bh = blockIdx.y;
  const int b = bh >> 4, h = bh & 15, hk = h >> 1;
  const int t = threadIdx.x, w = t >> 6, lane = t & 63;
  const int quad = lane >> 4, l16 = lane & 15;

  const ushort_t* qbase = Q + ((long)(b * HQ_ + h) * SEQ_) * HD_;
  const ushort_t* kbase = K + ((long)(b * HK_ + hk) * SEQ_) * HD_;
  const ushort_t* vtbase = VT + ((long)(b * HK_ + hk) * HD_) * SEQ_;

#define STAGEKV(bi, s0)                                                                     \
  for (int c = 0; c < 4; c++) {                                                             \
    int lin = c * 4096 + w * 1024 + lane * 16;                                              \
    int row = lin >> 8;                                                                     \
    int gc = (((lin >> 4) & 15) - row) & 15;                                                \
    glds16(kbase + (long)((s0) + row) * HD_ + gc * 8, (char*)Ks[bi] + c * 4096 + w * 1024); \
    int d = lin >> 7;                                                                       \
    int gc2 = (((lin >> 4) & 7) - d) & 7;                                                   \
    glds16(vtbase + (long)d * SEQ_ + (s0) + gc2 * 8, (char*)Vs[bi] + c * 4096 + w * 1024);  \
  }

  const f32x4 zero = {0.f, 0.f, 0.f, 0.f};

  for (int half = 0; half < 2; half++) {
    const int qi = half ? (int)blockIdx.x : 31 - (int)blockIdx.x;
    const int q0 = qi * 64;

    // stage Q tile (rows q0..q0+63) through Ks[0], 256B rows, 16-chunk rotate swizzle
    for (int c = 0; c < 4; c++) {
      int lin = c * 4096 + w * 1024 + lane * 16;
      int row = lin >> 8;
      int gc = (((lin >> 4) & 15) - row) & 15;
      glds16(qbase + (long)(q0 + row) * HD_ + gc * 8, (char*)Ks[0] + c * 4096 + w * 1024);
    }
    __syncthreads();
    bf16x8 qf[4];
    {
      int row = w * 16 + l16;
      for (int kk = 0; kk < 4; kk++) {
        int cl = (kk * 4 + quad + row) & 15;
        qf[kk] = *(const bf16x8*)((const char*)Ks[0] + row * 256 + cl * 16);
      }
    }
    __syncthreads();  // all waves hold Q frags; Ks[0] reusable

    f32x4 oa[8];
    for (int i = 0; i < 8; i++) oa[i] = zero;
    float rs[4] = {0.f, 0.f, 0.f, 0.f};

    const int nkt = qi + 1;
    STAGEKV(0, 0);
    __syncthreads();
    int buf = 0;
    for (int kt = 0; kt < nkt; kt++) {
      const int s0 = kt * 64;
      if (kt + 1 < nkt) STAGEKV(buf ^ 1, s0 + 64);
      const char* Kb = (const char*)Ks[buf];
      const char* Vb = (const char*)Vs[buf];

      f32x4 sa[4];
      __builtin_amdgcn_s_setprio(1);
      for (int cb = 0; cb < 4; cb++) {
        sa[cb] = zero;
        int n = cb * 16 + l16;
        for (int kk = 0; kk < 4; kk++) {
          int cl = (kk * 4 + quad + n) & 15;
          bf16x8 kfrag = *(const bf16x8*)(Kb + n * 256 + cl * 16);
          sa[cb] = MFMA(qf[kk], kfrag, sa[cb]);
        }
      }
      __builtin_amdgcn_s_setprio(0);
      if (kt == nkt - 1) {  // diagonal tile: mask col>row
        for (int cb = 0; cb < 4; cb++)
          for (int r = 0; r < 4; r++)
            if (cb * 16 + l16 > q0 + w * 16 + quad * 4 + r - s0) sa[cb][r] = -1e30f;
      }
      for (int cb = 0; cb < 4; cb++)
        for (int r = 0; r < 4; r++) {
          float p = exp2f(sa[cb][r]);
          rs[r] += p;
          Ps[w][quad * 4 + r][cb * 16 + l16] = f2bf(p);
        }
      __builtin_amdgcn_s_setprio(1);
      for (int kk2 = 0; kk2 < 2; kk2++) {
        bf16x8 pf = *(const bf16x8*)&Ps[w][l16][kk2 * 32 + quad * 8];
        for (int vb = 0; vb < 8; vb++) {
          int d = vb * 16 + l16;
          int cl = (kk2 * 4 + quad + d) & 7;
          bf16x8 vfrag = *(const bf16x8*)(Vb + d * 128 + cl * 16);
          oa[vb] = MFMA(pf, vfrag, oa[vb]);
        }
      }
      __builtin_amdgcn_s_setprio(0);
      __syncthreads();  // drains next-tile staging loads; buf^1 ready, buf free
      buf ^= 1;
    }

    float inv[4];
    int cr4[4];
    for (int r = 0; r < 4; r++) {
      float v = rs[r];
      v += __shfl_xor(v, 1);
      v += __shfl_xor(v, 2);
      v += __shfl_xor(v, 4);
      v += __shfl_xor(v, 8);
      inv[r] = 1.0f / v;
      cr4[r] = crow[b * SEQ_ + q0 + w * 16 + quad * 4 + r];
    }
    for (int vb = 0; vb < 8; vb++)
      for (int r = 0; r < 4; r++) {
        long off = (long)cr4[r] * 2048 + h * 128 + vb * 16 + l16;
        O[off] = f2bf(oa[vb][r] * inv[r]);
      }
  }
#undef STAGEKV
}

// ---------------- final RMSNorm over DIM, fp32 out ----------------
__global__ __launch_bounds__(256) void out_rmsnorm(const ushort_t* __restrict__ o_raw,
                                                   const int* __restrict__ crow,
                                                   const float* __restrict__ wn,
                                                   const int* __restrict__ ids,
                                                   float* __restrict__ out) {
  __shared__ float red[4];
  const int token = blockIdx.x;
  const int t = threadIdx.x, w = t >> 6, lane = t & 63;
  const int e = ids[token];
  const int cr = crow[token];
  ushort8 u = *(const ushort8*)(o_raw + (long)cr * 2048 + t * 8);
  float v[8];
  float ss = 0.f;
  for (int j = 0; j < 8; j++) {
    v[j] = bf2f(u[j]);
    ss += v[j] * v[j];
  }
  ss += __shfl_xor(ss, 32); ss += __shfl_xor(ss, 16); ss += __shfl_xor(ss, 8);
  ss += __shfl_xor(ss, 4);  ss += __shfl_xor(ss, 2);  ss += __shfl_xor(ss, 1);
  if (lane == 0) red[w] = ss;
  __syncthreads();
  float tot = red[0] + red[1] + red[2] + red[3];
  float r = rsqrtf(tot * (1.0f / 2048.0f) + 1e-6f);
  const float* wp = wn + (long)e * 2048 + t * 8;
  float* op = out + (long)token * 2048 + t * 8;
  for (int j = 0; j < 8; j++) op[j] = v[j] * r * wp[j];
}

extern "C" void kernel_launch(void* const* d_in, const int* in_sizes, int n_in, void* d_out,
                              int out_size, void* d_ws, size_t ws_size, hipStream_t stream) {
  const float* x = (const float*)d_in[0];
  const float* fc = (const float*)d_in[1];
  const float* fs = (const float*)d_in[2];
  const float* wq = (const float*)d_in[3];
  const float* wk = (const float*)d_in[4];
  const float* wv = (const float*)d_in[5];
  const float* wo = (const float*)d_in[6];
  const float* qnw = (const float*)d_in[7];
  const float* knw = (const float*)d_in[8];
  const float* anw = (const float*)d_in[9];
  const int* ids = (const int*)d_in[10];
  float* out = (float*)d_out;
  char* ws = (char*)d_ws;

  ushort_t* x_bf = (ushort_t*)(ws + 0);             // 16 MB (compact rows)
  ushort_t* wqkvT = (ushort_t*)(ws + (16l << 20));  // 32 MB (E x 4096 x 2048)
  ushort_t* woT = (ushort_t*)(ws + (16l << 20));    // 16 MB, reuses wqkvT after QKV GEMM
  int* cnt = (int*)(ws + (48l << 20));              // 8 B
  int* crow = (int*)(ws + (48l << 20) + 64);        // 16 KB
  ushort_t* qkvraw = (ushort_t*)(ws + (64l << 20)); // 32 MB (compact rows x 4096)
  ushort_t* qfh = (ushort_t*)(ws + (96l << 20));    // 16 MB  [b][hq][s][d]
  ushort_t* kfh = (ushort_t*)(ws + (112l << 20));   // 8 MB   [b][hk][s][d]
  ushort_t* vt = (ushort_t*)(ws + (120l << 20));    // 8 MB   [b][hk][d][s]
  ushort_t* o_flat = x_bf;
  ushort_t* o_raw = qkvraw;

  build_crow<<<1, 1024, 0, stream>>>(ids, cnt, crow);
  convert_scatter<<<NTOK, 256, 0, stream>>>(x, crow, x_bf);
  transpose_w3<<<dim3(128, 64, E_), 256, 0, stream>>>(wq, wk, wv, wqkvT);
  gemm_bt_slot<<<dim3(32, 33), 256, 0, stream>>>(x_bf, wqkvT, qkvraw, 2048, 4096, cnt,
                                                 (long)4096 * 2048);
  transpose_f2b<<<dim3(64, 64, E_), 256, 0, stream>>>(wo, woT, 2048, 2048, (long)2048 * 2048,
                                                      (long)2048 * 2048, 0);
  fuse_rmsrope<<<NTOK, 256, 0, stream>>>(qkvraw, crow, qnw, knw, fc, fs, ids, qfh, kfh);
  transpose_v<<<dim3(64, 4, BS_ * HK_), 256, 0, stream>>>(qkvraw, crow, vt);
  attn_kernel<<<dim3(16, 32), 256, 0, stream>>>(qfh, kfh, vt, crow, o_flat);
  gemm_bt_slot<<<dim3(16, 33), 256, 0, stream>>>(o_flat, woT, o_raw, 2048, 2048, cnt,
                                                 (long)2048 * 2048);
  out_rmsnorm<<<NTOK, 256, 0, stream>>>(o_raw, crow, anw, ids, out);
}

// Round 16
// 429.158 us; speedup vs baseline: 1.0180x; 1.0180x over previous
//
#include <hip/hip_runtime.h>

#define E_ 2
#define HQ_ 16
#define HK_ 8
#define HD_ 128
#define DIM_ 2048
#define BS_ 2
#define SEQ_ 2048
#define NTOK 4096

typedef unsigned short ushort_t;
typedef short bf16x8 __attribute__((ext_vector_type(8)));
typedef unsigned short ushort8 __attribute__((ext_vector_type(8)));
typedef float f32x4 __attribute__((ext_vector_type(4)));

#define MFMA(a, b, c) __builtin_amdgcn_mfma_f32_16x16x32_bf16(a, b, c, 0, 0, 0)

__device__ __forceinline__ unsigned short f2bf(float f) {
  unsigned u = __builtin_bit_cast(unsigned, f);
  u = (u + 0x7FFFu + ((u >> 16) & 1u)) >> 16;
  return (unsigned short)u;
}
__device__ __forceinline__ float bf2f(unsigned short h) {
  unsigned u = ((unsigned)h) << 16;
  return __builtin_bit_cast(float, u);
}

__device__ __forceinline__ void glds16(const void* g, void* s) {
  __builtin_amdgcn_global_load_lds(
      (const __attribute__((address_space(1))) unsigned int*)g,
      (__attribute__((address_space(3))) unsigned int*)s, 16, 0, 0);
}

// ---------------- token -> compact row (expert-0 rows first), deterministic scan ----------------
__global__ __launch_bounds__(1024) void build_crow(const int* __restrict__ ids,
                                                   int* __restrict__ cnt, int* __restrict__ crow) {
  __shared__ int sc[1024];
  __shared__ int total0;
  const int t = threadIdx.x;
  int id4[4];
  int c = 0;
  for (int j = 0; j < 4; j++) {
    id4[j] = ids[t * 4 + j];
    c += (id4[j] == 0);
  }
  sc[t] = c;
  __syncthreads();
  for (int off = 1; off < 1024; off <<= 1) {
    int v = sc[t];
    int add = (t >= off) ? sc[t - off] : 0;
    __syncthreads();
    sc[t] = v + add;
    __syncthreads();
  }
  if (t == 1023) total0 = sc[1023];
  __syncthreads();
  const int cnt0 = total0;
  if (t == 0) {
    cnt[0] = cnt0;
    cnt[1] = NTOK - cnt0;
  }
  int p0 = sc[t] - c;
  int r0 = 0;
  for (int j = 0; j < 4; j++) {
    int n = t * 4 + j;
    int cr;
    if (id4[j] == 0) {
      cr = p0 + r0;
      r0++;
    } else {
      cr = cnt0 + (n - (p0 + r0));
    }
    crow[n] = cr;
  }
}

// ---------------- x fp32 -> bf16, scattered into compact row order ----------------
__global__ __launch_bounds__(256) void convert_scatter(const float* __restrict__ x,
                                                       const int* __restrict__ crow,
                                                       ushort_t* __restrict__ xb) {
  const int token = blockIdx.x;
  const int cr = crow[token];
  const long src = (long)token * DIM_ + threadIdx.x * 8;
  const long dst = (long)cr * DIM_ + threadIdx.x * 8;
  float4 a = *(const float4*)(x + src);
  float4 b = *(const float4*)(x + src + 4);
  ushort8 o;
  o[0] = f2bf(a.x); o[1] = f2bf(a.y); o[2] = f2bf(a.z); o[3] = f2bf(a.w);
  o[4] = f2bf(b.x); o[5] = f2bf(b.y); o[6] = f2bf(b.z); o[7] = f2bf(b.w);
  *(ushort8*)(xb + dst) = o;
}

// ---------------- merged wq/wk/wv [e][K][N] fp32 -> wqkvT [e][outBase+n][K] bf16 ----------------
// One launch instead of three. Block-uniform source select.
__global__ __launch_bounds__(256) void transpose_w3(const float* __restrict__ wq,
                                                    const float* __restrict__ wk,
                                                    const float* __restrict__ wv,
                                                    ushort_t* __restrict__ out) {
  __shared__ float tile[32][33];
  const int e = blockIdx.z;
  const int xx = blockIdx.x;
  const float* inp;
  int N, outBase, n0;
  if (xx < 64) {
    inp = wq + (long)e * 2048 * 2048; N = 2048; outBase = 0;    n0 = xx * 32;
  } else if (xx < 96) {
    inp = wk + (long)e * 2048 * 1024; N = 1024; outBase = 2048; n0 = (xx - 64) * 32;
  } else {
    inp = wv + (long)e * 2048 * 1024; N = 1024; outBase = 3072; n0 = (xx - 96) * 32;
  }
  ushort_t* outp = out + (long)e * 4096 * 2048;
  const int k0 = blockIdx.y * 32;
  const int tx = threadIdx.x & 31, ty = threadIdx.x >> 5;
  for (int i = 0; i < 4; i++)
    tile[ty + i * 8][tx] = inp[(long)(k0 + ty + i * 8) * N + n0 + tx];
  __syncthreads();
  for (int i = 0; i < 4; i++)
    outp[(long)(outBase + n0 + ty + i * 8) * 2048 + k0 + tx] = f2bf(tile[tx][ty + i * 8]);
}

// ---------------- W [e][K][N] fp32 -> W^T [e][outBase+n][K] bf16 (wo only) ----------------
__global__ __launch_bounds__(256) void transpose_f2b(const float* __restrict__ in,
                                                     ushort_t* __restrict__ out, int K, int N,
                                                     long inE, long outE, int outBase) {
  __shared__ float tile[32][33];
  int e = blockIdx.z;
  const float* inp = in + (long)e * inE;
  ushort_t* outp = out + (long)e * outE;
  int n0 = blockIdx.x * 32, k0 = blockIdx.y * 32;
  int tx = threadIdx.x & 31, ty = threadIdx.x >> 5;
  for (int i = 0; i < 4; i++)
    tile[ty + i * 8][tx] = inp[(long)(k0 + ty + i * 8) * N + n0 + tx];
  __syncthreads();
  for (int i = 0; i < 4; i++)
    outp[(long)(outBase + n0 + ty + i * 8) * K + k0 + tx] = f2bf(tile[tx][ty + i * 8]);
}

// ---------------- v slice of qkv_raw (compact rows) -> V^T [b][hk][d][s] bf16 ----------------
__global__ __launch_bounds__(256) void transpose_v(const ushort_t* __restrict__ qkv,
                                                   const int* __restrict__ crow,
                                                   ushort_t* __restrict__ vt) {
  __shared__ ushort_t tile[32][34];
  int z = blockIdx.z;
  int b = z / HK_, hk = z % HK_;
  int s0 = blockIdx.x * 32, d0 = blockIdx.y * 32;
  int tx = threadIdx.x & 31, ty = threadIdx.x >> 5;
  for (int i = 0; i < 4; i++) {
    int cr = crow[b * SEQ_ + s0 + ty + i * 8];
    tile[ty + i * 8][tx] = qkv[(long)cr * 4096 + 3072 + hk * 128 + d0 + tx];
  }
  __syncthreads();
  for (int i = 0; i < 4; i++)
    vt[((long)(b * HK_ + hk) * 128 + d0 + ty + i * 8) * SEQ_ + s0 + tx] = tile[tx][ty + i * 8];
}

// ---------------- per-expert GEMM, 128x128 tile, 4 waves, 64x64/wave, 3 blocks/CU ----------
// Best-measured engine (431.7/432.3 us totals). ~660 TF = 2-phase-class structural plateau for
// these K=2048 per-expert shapes; all deeper-pipeline escapes failed on occupancy/spill/boundary.
__global__ __launch_bounds__(256, 3) void gemm_bt_slot(const ushort_t* __restrict__ A,
                                                       const ushort_t* __restrict__ BT,
                                                       ushort_t* __restrict__ C, int K, int Nc,
                                                       const int* __restrict__ cnt, long btE) {
  __shared__ __align__(16) char lds[49152];
  const int cnt0 = cnt[0];
  const int nA = (cnt0 + 127) >> 7;
  const int slot = blockIdx.y, bn = blockIdx.x;
  const int e = (slot < nA) ? 0 : 1;
  const int bm = e ? slot - nA : slot;
  const int scnt = e ? (NTOK - cnt0) : cnt0;
  if (bm * 128 >= scnt) return;
  const int sbase = e ? cnt0 : 0;
  const ushort_t* Bte = BT + (long)e * btE;

  const int t = threadIdx.x, w = t >> 6, lane = t & 63;
  const int quad = lane >> 4, l16 = lane & 15;
  const int wr = w >> 1, wc = w & 1;  // wave grid: 2 (M of 64) x 2 (N of 64)

  const int arow0 = sbase + bm * 128;
  const int brow0 = bn * 128;

  // staging: unit = 128 rows x 32 k (64B rows, 4x16B chunks, rotate row>>1).
  const int srow = t >> 2;                       // 0..63
  const int lc = ((t & 3) - (srow >> 1)) & 3;    // chunk landing at this thread's slot
  int ga1 = arow0 + srow;       if (ga1 > NTOK - 1) ga1 = NTOK - 1;
  int ga2 = arow0 + 64 + srow;  if (ga2 > NTOK - 1) ga2 = NTOK - 1;
  const ushort_t* sA1 = A + (long)ga1 * K + lc * 8;
  const ushort_t* sA2 = A + (long)ga2 * K + lc * 8;
  const ushort_t* sB1 = Bte + (long)(brow0 + srow) * K + lc * 8;
  const ushort_t* sB2 = Bte + (long)(brow0 + 64 + srow) * K + lc * 8;

  f32x4 acc[4][4];
#pragma unroll
  for (int i = 0; i < 4; i++)
#pragma unroll
    for (int j = 0; j < 4; j++) acc[i][j] = (f32x4){0.f, 0.f, 0.f, 0.f};

#define STAGE(ps, kk)                                \
  glds16(sA1 + (kk), (ps) + w * 1024);               \
  glds16(sA2 + (kk), (ps) + 4096 + w * 1024);        \
  glds16(sB1 + (kk), (ps) + 8192 + w * 1024);        \
  glds16(sB2 + (kk), (ps) + 12288 + w * 1024);

  char* pr = lds;
  char* pn = lds + 16384;
  char* p2 = lds + 32768;

  // prologue: stage kt0, kt1; wait kt0 complete (4 of 8 outstanding)
  STAGE(pr, 0);
  STAGE(pn, 32);
  asm volatile("s_waitcnt vmcnt(4)" ::: "memory");
  __builtin_amdgcn_s_barrier();

  const int NT = K >> 5;
  for (int kt = 0; kt < NT; kt++) {
    const bool st = (kt + 2) < NT;
    if (st) { STAGE(p2, (kt + 2) * 32); }
    bf16x8 af[4], bfv[4];
#pragma unroll
    for (int mf = 0; mf < 4; mf++) {
      const int lr = wr * 64 + mf * 16 + l16;
      af[mf] = *(const bf16x8*)(pr + lr * 64 + ((quad + (lr >> 1)) & 3) * 16);
    }
#pragma unroll
    for (int nf = 0; nf < 4; nf++) {
      const int c = wc * 64 + nf * 16 + l16;
      bfv[nf] = *(const bf16x8*)(pr + 8192 + c * 64 + ((quad + (c >> 1)) & 3) * 16);
    }
    asm volatile("s_waitcnt lgkmcnt(0)" ::: "memory");
    __builtin_amdgcn_sched_barrier(0);
    __builtin_amdgcn_s_setprio(1);
#pragma unroll
    for (int mf = 0; mf < 4; mf++)
#pragma unroll
      for (int nf = 0; nf < 4; nf++) acc[mf][nf] = MFMA(af[mf], bfv[nf], acc[mf][nf]);
    __builtin_amdgcn_s_setprio(0);
    if (st) asm volatile("s_waitcnt vmcnt(4)" ::: "memory");
    else    asm volatile("s_waitcnt vmcnt(0)" ::: "memory");
    __builtin_amdgcn_s_barrier();
    char* tmp = pr; pr = pn; pn = p2; p2 = tmp;
  }
#undef STAGE

  // epilogue: C/D layout col=lane&15, row=quad*4+reg
#pragma unroll
  for (int mf = 0; mf < 4; mf++) {
#pragma unroll
    for (int reg = 0; reg < 4; reg++) {
      const int rl = wr * 64 + mf * 16 + quad * 4 + reg;
      if (bm * 128 + rl >= scnt) continue;
      ushort_t* Cp = C + (long)(arow0 + rl) * Nc + brow0 + wc * 64 + l16;
#pragma unroll
      for (int nf = 0; nf < 4; nf++) Cp[nf * 16] = f2bf(acc[mf][nf][reg]);
    }
  }
}

// ---------------- per-head RMSNorm + RoPE ----------------
__global__ __launch_bounds__(256) void fuse_rmsrope(
    const ushort_t* __restrict__ qkv, const int* __restrict__ crow, const float* __restrict__ qw,
    const float* __restrict__ kw, const float* __restrict__ fc, const float* __restrict__ fs,
    const int* __restrict__ ids, ushort_t* __restrict__ qout, ushort_t* __restrict__ kout) {
  const int token = blockIdx.x;
  const int slot = blockIdx.y * 4 + (threadIdx.x >> 6);
  const int lane = threadIdx.x & 63;
  const int b = token >> 11, s = token & 2047;
  const int e = ids[token];
  const int cr = crow[token];
  const bool isq = slot < 16;
  const int h = isq ? slot : slot - 16;
  const ushort_t* src = qkv + (long)cr * 4096 + (isq ? slot * 128 : 2048 + h * 128);
  unsigned pv = *(const unsigned*)(src + 2 * lane);
  float v0 = bf2f((unsigned short)pv), v1 = bf2f((unsigned short)(pv >> 16));
  float ss = v0 * v0 + v1 * v1;
  ss += __shfl_xor(ss, 32); ss += __shfl_xor(ss, 16); ss += __shfl_xor(ss, 8);
  ss += __shfl_xor(ss, 4);  ss += __shfl_xor(ss, 2);  ss += __shfl_xor(ss, 1);
  float r = rsqrtf(ss * (1.0f / 128.0f) + 1e-6f);
  const float* nw = (isq ? qw : kw) + e * 128;
  v0 *= r * nw[2 * lane];
  v1 *= r * nw[2 * lane + 1];
  float c = fc[s * 64 + lane], sn = fs[s * 64 + lane];
  float o0 = v0 * c - v1 * sn;
  float o1 = v0 * sn + v1 * c;
  ushort_t* dst;
  if (isq) {
    const float QS = 0.08838834764831845f * 1.4426950408889634f;  // 1/sqrt(128)*log2(e)
    o0 *= QS; o1 *= QS;
    dst = qout + ((long)(b * HQ_ + h) * SEQ_ + s) * 128;
  } else {
    dst = kout + ((long)(b * HK_ + h) * SEQ_ + s) * 128;
  }
  *(unsigned*)(dst + 2 * lane) = (unsigned)f2bf(o0) | ((unsigned)f2bf(o1) << 16);
}

// ---------------- causal GQA flash attention, BM=BN=64 ----------------
// (validated: paired q-tiles, 2-phase double-buffered K/V staging, setprio on MFMA clusters)
__global__ __launch_bounds__(256, 2) void attn_kernel(const ushort_t* __restrict__ Q,
                                                      const ushort_t* __restrict__ K,
                                                      const ushort_t* __restrict__ VT,
                                                      const int* __restrict__ crow,
                                                      ushort_t* __restrict__ O) {
  __shared__ __align__(16) ushort_t Ks[2][64 * 128];
  __shared__ __align__(16) ushort_t Vs[2][128 * 64];
  __shared__ __align__(16) ushort_t Ps[4][16][72];  // per-wave P, padded stride

  const int bh = blockIdx.y;
  const int b = bh >> 4, h = bh & 15, hk = h >> 1;
  const int t = threadIdx.x, w = t >> 6, lane = t & 63;
  const int quad = lane >> 4, l16 = lane & 15;

  const ushort_t* qbase = Q + ((long)(b * HQ_ + h) * SEQ_) * HD_;
  const ushort_t* kbase = K + ((long)(b * HK_ + hk) * SEQ_) * HD_;
  const ushort_t* vtbase = VT + ((long)(b * HK_ + hk) * HD_) * SEQ_;

#define STAGEKV(bi, s0)                                                                     \
  for (int c = 0; c < 4; c++) {                                                             \
    int lin = c * 4096 + w * 1024 + lane * 16;                                              \
    int row = lin >> 8;                                                                     \
    int gc = (((lin >> 4) & 15) - row) & 15;                                                \
    glds16(kbase + (long)((s0) + row) * HD_ + gc * 8, (char*)Ks[bi] + c * 4096 + w * 1024); \
    int d = lin >> 7;                                                                       \
    int gc2 = (((lin >> 4) & 7) - d) & 7;                                                   \
    glds16(vtbase + (long)d * SEQ_ + (s0) + gc2 * 8, (char*)Vs[bi] + c * 4096 + w * 1024);  \
  }

  const f32x4 zero = {0.f, 0.f, 0.f, 0.f};

  for (int half = 0; half < 2; half++) {
    const int qi = half ? (int)blockIdx.x : 31 - (int)blockIdx.x;
    const int q0 = qi * 64;

    // stage Q tile (rows q0..q0+63) through Ks[0], 256B rows, 16-chunk rotate swizzle
    for (int c = 0; c < 4; c++) {
      int lin = c * 4096 + w * 1024 + lane * 16;
      int row = lin >> 8;
      int gc = (((lin >> 4) & 15) - row) & 15;
      glds16(qbase + (long)(q0 + row) * HD_ + gc * 8, (char*)Ks[0] + c * 4096 + w * 1024);
    }
    __syncthreads();
    bf16x8 qf[4];
    {
      int row = w * 16 + l16;
      for (int kk = 0; kk < 4; kk++) {
        int cl = (kk * 4 + quad + row) & 15;
        qf[kk] = *(const bf16x8*)((const char*)Ks[0] + row * 256 + cl * 16);
      }
    }
    __syncthreads();  // all waves hold Q frags; Ks[0] reusable

    f32x4 oa[8];
    for (int i = 0; i < 8; i++) oa[i] = zero;
    float rs[4] = {0.f, 0.f, 0.f, 0.f};

    const int nkt = qi + 1;
    STAGEKV(0, 0);
    __syncthreads();
    int buf = 0;
    for (int kt = 0; kt < nkt; kt++) {
      const int s0 = kt * 64;
      if (kt + 1 < nkt) STAGEKV(buf ^ 1, s0 + 64);
      const char* Kb = (const char*)Ks[buf];
      const char* Vb = (const char*)Vs[buf];

      f32x4 sa[4];
      __builtin_amdgcn_s_setprio(1);
      for (int cb = 0; cb < 4; cb++) {
        sa[cb] = zero;
        int n = cb * 16 + l16;
        for (int kk = 0; kk < 4; kk++) {
          int cl = (kk * 4 + quad + n) & 15;
          bf16x8 kfrag = *(const bf16x8*)(Kb + n * 256 + cl * 16);
          sa[cb] = MFMA(qf[kk], kfrag, sa[cb]);
        }
      }
      __builtin_amdgcn_s_setprio(0);
      if (kt == nkt - 1) {  // diagonal tile: mask col>row
        for (int cb = 0; cb < 4; cb++)
          for (int r = 0; r < 4; r++)
            if (cb * 16 + l16 > q0 + w * 16 + quad * 4 + r - s0) sa[cb][r] = -1e30f;
      }
      for (int cb = 0; cb < 4; cb++)
        for (int r = 0; r < 4; r++) {
          float p = exp2f(sa[cb][r]);
          rs[r] += p;
          Ps[w][quad * 4 + r][cb * 16 + l16] = f2bf(p);
        }
      __builtin_amdgcn_s_setprio(1);
      for (int kk2 = 0; kk2 < 2; kk2++) {
        bf16x8 pf = *(const bf16x8*)&Ps[w][l16][kk2 * 32 + quad * 8];
        for (int vb = 0; vb < 8; vb++) {
          int d = vb * 16 + l16;
          int cl = (kk2 * 4 + quad + d) & 7;
          bf16x8 vfrag = *(const bf16x8*)(Vb + d * 128 + cl * 16);
          oa[vb] = MFMA(pf, vfrag, oa[vb]);
        }
      }
      __builtin_amdgcn_s_setprio(0);
      __syncthreads();  // drains next-tile staging loads; buf^1 ready, buf free
      buf ^= 1;
    }

    float inv[4];
    int cr4[4];
    for (int r = 0; r < 4; r++) {
      float v = rs[r];
      v += __shfl_xor(v, 1);
      v += __shfl_xor(v, 2);
      v += __shfl_xor(v, 4);
      v += __shfl_xor(v, 8);
      inv[r] = 1.0f / v;
      cr4[r] = crow[b * SEQ_ + q0 + w * 16 + quad * 4 + r];
    }
    for (int vb = 0; vb < 8; vb++)
      for (int r = 0; r < 4; r++) {
        long off = (long)cr4[r] * 2048 + h * 128 + vb * 16 + l16;
        O[off] = f2bf(oa[vb][r] * inv[r]);
      }
  }
#undef STAGEKV
}

// ---------------- final RMSNorm over DIM, fp32 out ----------------
__global__ __launch_bounds__(256) void out_rmsnorm(const ushort_t* __restrict__ o_raw,
                                                   const int* __restrict__ crow,
                                                   const float* __restrict__ wn,
                                                   const int* __restrict__ ids,
                                                   float* __restrict__ out) {
  __shared__ float red[4];
  const int token = blockIdx.x;
  const int t = threadIdx.x, w = t >> 6, lane = t & 63;
  const int e = ids[token];
  const int cr = crow[token];
  ushort8 u = *(const ushort8*)(o_raw + (long)cr * 2048 + t * 8);
  float v[8];
  float ss = 0.f;
  for (int j = 0; j < 8; j++) {
    v[j] = bf2f(u[j]);
    ss += v[j] * v[j];
  }
  ss += __shfl_xor(ss, 32); ss += __shfl_xor(ss, 16); ss += __shfl_xor(ss, 8);
  ss += __shfl_xor(ss, 4);  ss += __shfl_xor(ss, 2);  ss += __shfl_xor(ss, 1);
  if (lane == 0) red[w] = ss;
  __syncthreads();
  float tot = red[0] + red[1] + red[2] + red[3];
  float r = rsqrtf(tot * (1.0f / 2048.0f) + 1e-6f);
  const float* wp = wn + (long)e * 2048 + t * 8;
  float* op = out + (long)token * 2048 + t * 8;
  for (int j = 0; j < 8; j++) op[j] = v[j] * r * wp[j];
}

extern "C" void kernel_launch(void* const* d_in, const int* in_sizes, int n_in, void* d_out,
                              int out_size, void* d_ws, size_t ws_size, hipStream_t stream) {
  const float* x = (const float*)d_in[0];
  const float* fc = (const float*)d_in[1];
  const float* fs = (const float*)d_in[2];
  const float* wq = (const float*)d_in[3];
  const float* wk = (const float*)d_in[4];
  const float* wv = (const float*)d_in[5];
  const float* wo = (const float*)d_in[6];
  const float* qnw = (const float*)d_in[7];
  const float* knw = (const float*)d_in[8];
  const float* anw = (const float*)d_in[9];
  const int* ids = (const int*)d_in[10];
  float* out = (float*)d_out;
  char* ws = (char*)d_ws;

  ushort_t* x_bf = (ushort_t*)(ws + 0);             // 16 MB (compact rows)
  ushort_t* wqkvT = (ushort_t*)(ws + (16l << 20));  // 32 MB (E x 4096 x 2048)
  ushort_t* woT = (ushort_t*)(ws + (16l << 20));    // 16 MB, reuses wqkvT after QKV GEMM
  int* cnt = (int*)(ws + (48l << 20));              // 8 B
  int* crow = (int*)(ws + (48l << 20) + 64);        // 16 KB
  ushort_t* qkvraw = (ushort_t*)(ws + (64l << 20)); // 32 MB (compact rows x 4096)
  ushort_t* qfh = (ushort_t*)(ws + (96l << 20));    // 16 MB  [b][hq][s][d]
  ushort_t* kfh = (ushort_t*)(ws + (112l << 20));   // 8 MB   [b][hk][s][d]
  ushort_t* vt = (ushort_t*)(ws + (120l << 20));    // 8 MB   [b][hk][d][s]
  ushort_t* o_flat = x_bf;
  ushort_t* o_raw = qkvraw;

  build_crow<<<1, 1024, 0, stream>>>(ids, cnt, crow);
  convert_scatter<<<NTOK, 256, 0, stream>>>(x, crow, x_bf);
  transpose_w3<<<dim3(128, 64, E_), 256, 0, stream>>>(wq, wk, wv, wqkvT);
  gemm_bt_slot<<<dim3(32, 33), 256, 0, stream>>>(x_bf, wqkvT, qkvraw, 2048, 4096, cnt,
                                                 (long)4096 * 2048);
  transpose_f2b<<<dim3(64, 64, E_), 256, 0, stream>>>(wo, woT, 2048, 2048, (long)2048 * 2048,
                                                      (long)2048 * 2048, 0);
  fuse_rmsrope<<<dim3(NTOK, 6), 256, 0, stream>>>(qkvraw, crow, qnw, knw, fc, fs, ids, qfh, kfh);
  transpose_v<<<dim3(64, 4, BS_ * HK_), 256, 0, stream>>>(qkvraw, crow, vt);
  attn_kernel<<<dim3(16, 32), 256, 0, stream>>>(qfh, kfh, vt, crow, o_flat);
  gemm_bt_slot<<<dim3(16, 33), 256, 0, stream>>>(o_flat, woT, o_raw, 2048, 2048, cnt,
                                                 (long)2048 * 2048);
  out_rmsnorm<<<NTOK, 256, 0, stream>>>(o_raw, crow, anw, ids, out);
}